// Round 3
// baseline (235.825 us; speedup 1.0000x reference)
//
#include <hip/hip_runtime.h>

#define TPB 256
#define NP  34
#define D3  156
#define NNZ 832
#define DIN 16
#define NC  16
#define RSPLIT 4                    // row-quartile split: one wave per quartile
#define EPB 4                       // edges per block (TPB / (NC*RSPLIT))
#define TSTR (NNZ + 8)              // 840: el*840 % 32 = el*8 -> the 4 el-groups
                                    // read distinct banks; c-groups broadcast.

// The CG sparsity pattern (selection rule |m1+m2| == |m3| over LS=(0,1,2,3),
// LMAX_OUT=3) is deterministic — only the cg VALUES are random. Build the
// structure at compile time so the k-loop fully unrolls with constant indices.
struct CGStruct {
    unsigned char  mu1[NNZ];      // global d1 index per entry (row-major-sorted)
    unsigned char  mu2[NNZ];      // global d2 index per entry
    unsigned char  rowlen[D3];    // entries per output row m3
    unsigned char  rowpath[D3];   // path id per output row
    unsigned short rowk[D3];      // entry offset of each row (prefix sum)
};

constexpr CGStruct build_cg() {
    CGStruct s{};
    int offs[4] = {0, 1, 4, 9};          // cumsum of 2l+1 for l=0..3
    int off3 = 0, path = 0, k = 0;
    for (int i = 0; i < 4; ++i) {
        int l1 = i;
        for (int j = 0; j < 4; ++j) {
            int l2 = j;
            int lo = l1 - l2; if (lo < 0) lo = -lo;
            int hi = l1 + l2; if (hi > 3) hi = 3;
            for (int l3 = lo; l3 <= hi; ++l3) {
                int d1 = 2 * l1 + 1, d2 = 2 * l2 + 1, d3 = 2 * l3 + 1;
                // stable argsort by i3 == iterate i3 outer, then (i1,i2) in
                // original meshgrid order
                for (int i3 = 0; i3 < d3; ++i3) {
                    s.rowk[off3 + i3] = (unsigned short)k;
                    int cnt = 0;
                    for (int i1 = 0; i1 < d1; ++i1)
                        for (int i2 = 0; i2 < d2; ++i2) {
                            int m12 = (i1 - l1) + (i2 - l2);
                            if (m12 < 0) m12 = -m12;
                            int m3 = i3 - l3; if (m3 < 0) m3 = -m3;
                            if (m12 == m3) {
                                s.mu1[k] = (unsigned char)(i1 + offs[i]);
                                s.mu2[k] = (unsigned char)(i2 + offs[j]);
                                ++k; ++cnt;
                            }
                        }
                    s.rowlen[off3 + i3]  = (unsigned char)cnt;
                    s.rowpath[off3 + i3] = (unsigned char)path;
                }
                off3 += d3;
                ++path;
            }
        }
    }
    return s;
}

constexpr CGStruct CGS = build_cg();

// One row-quartile worth of rows (r = Q, Q+4, ...), fully unrolled with
// compile-time k offsets. The cg*y product comes pre-combined from LDS
// (tsh broadcast read, imm offset); per-entry work is ONE fma + one ds_read
// instead of 2 VALU + 1 s_load.
template<int Q>
__device__ __forceinline__ void do_rows(const float* __restrict__ trow,  // &tsh[el*TSTR]
                                        const float* __restrict__ wrow,  // &wsh[c]
                                        float* __restrict__ outp,
                                        const float (&xv)[DIN])
{
#pragma unroll
    for (int r = Q; r < D3; r += RSPLIT) {
        float acc = 0.f;
        int k = CGS.rowk[r];
#pragma unroll
        for (int q = 0; q < CGS.rowlen[r]; ++q) {
            // trow[k]: compile-time imm offset; 16-lane c-group broadcast,
            // 4 el-groups on distinct banks (TSTR pad) -> conflict-free
            acc += trow[k] * xv[CGS.mu1[k]];
            ++k;
        }
        outp[(size_t)r * NC] = acc * wrow[CGS.rowpath[r] * NC];
    }
}

__global__ __launch_bounds__(TPB)
void tp_kernel(const float* __restrict__ x, const float* __restrict__ y,
               const float* __restrict__ cg, const float* __restrict__ wts,
               float* __restrict__ out, int E)
{
    // weights transposed: wsh[path][c] -> c-groups read 16 consecutive dwords,
    // el-groups broadcast: conflict-free
    __shared__ float wsh[NP * NC];
    // shared cg*y products: tsh[el][k], padded stride
    __shared__ float tsh[EPB * TSTR];

    const int t = threadIdx.x;
    const int eBase = blockIdx.x * EPB;

    for (int i = t; i < NP * NC; i += TPB) {
        int p = i >> 4, cc = i & 15;
        wsh[i] = wts[cc * NP + p];
    }

    // Phase 1: tsh[el*TSTR + k] = cg[k] * y[eBase+el][mu2[k]].
    // cg[k] coalesced dword loads; y gather stays inside one 64B line per
    // el (DIN=16 floats). 13 entries/thread — removes the per-wave 832-deep
    // s_load stream and the 16x-redundant cg*y multiplies from the hot loop.
    for (int k = t; k < NNZ; k += TPB) {
        float cgv = cg[k];
        int m2 = (int)CGS.mu2[k];            // runtime-indexed -> .rodata load
#pragma unroll
        for (int el = 0; el < EPB; ++el) {
            int ee = eBase + el; if (ee > E - 1) ee = E - 1;   // tail-safe
            tsh[el * TSTR + k] = cgv * y[(size_t)ee * DIN + m2];
        }
    }
    __syncthreads();

    const int c  = t & 15;               // channel
    const int el = (t >> 4) & (EPB - 1); // edge within block (varies in-wave)
    const int rq = t >> 6;               // wave id == row quartile (uniform/wave)
    const int e  = eBase + el;
    if (e >= E) return;

    // x[e,:,c] in registers; all later indexing compile-time so SROA keeps
    // it in VGPRs.
    float xv[DIN];
    const float* xp = x + (size_t)e * (DIN * NC) + c;
#pragma unroll
    for (int d = 0; d < DIN; ++d) xv[d] = xp[d * NC];   // coalesced 64B per c-group

    float* outp = out + (size_t)e * (D3 * NC) + c;
    const float* trow = &tsh[el * TSTR];
    const float* wrow = &wsh[c];

    // rq is wave-uniform: each wave executes exactly one code region.
    switch (rq) {
        case 0: do_rows<0>(trow, wrow, outp, xv); break;
        case 1: do_rows<1>(trow, wrow, outp, xv); break;
        case 2: do_rows<2>(trow, wrow, outp, xv); break;
        case 3: do_rows<3>(trow, wrow, outp, xv); break;
    }
}

extern "C" void kernel_launch(void* const* d_in, const int* in_sizes, int n_in,
                              void* d_out, int out_size, void* d_ws, size_t ws_size,
                              hipStream_t stream)
{
    const float* x   = (const float*)d_in[0];
    const float* y   = (const float*)d_in[1];
    const float* cg  = (const float*)d_in[2];
    const float* wts = (const float*)d_in[3];
    float* out = (float*)d_out;

    const int E = in_sizes[1] / DIN;          // 20000

    dim3 grid((E + EPB - 1) / EPB), block(TPB);
    hipLaunchKernelGGL(tp_kernel, grid, block, 0, stream,
                       x, y, cg, wts, out, E);
}